// Round 8
// baseline (130.659 us; speedup 1.0000x reference)
//
#include <hip/hip_runtime.h>
#include <math.h>

constexpr int NB = 1024;   // batch
constexpr int NT = 256;    // topic_size
constexpr int NE = 300;    // embedding_size
constexpr int NBATCH = 2;  // batches per k_main block

#if defined(__has_builtin)
#if __has_builtin(__builtin_amdgcn_exp2f)
#define EXP2F(x) __builtin_amdgcn_exp2f(x)
#else
#define EXP2F(x) exp2f(x)
#endif
#if __has_builtin(__builtin_amdgcn_logf)
#define LOG2F(x) __builtin_amdgcn_logf(x)
#else
#define LOG2F(x) log2f(x)
#endif
#else
#define EXP2F(x) exp2f(x)
#define LOG2F(x) log2f(x)
#endif

typedef float f32x2 __attribute__((ext_vector_type(2)));

__device__ __forceinline__ float rdlane(float v, int l) {
  return __uint_as_float(__builtin_amdgcn_readlane(__float_as_uint(v), l));
}
__device__ __forceinline__ f32x2 pk_fma(f32x2 a, f32x2 b, f32x2 c) {
  return __builtin_elementwise_fma(a, b, c);  // -> v_pk_fma_f32 (gfx90a+)
}

// ===== k_M: column blk of M. Mt[blk][t]=sum_e TE[e,t]*wf[blk,e].  (r7, proven)
__global__ __launch_bounds__(1024) void k_M(const float* __restrict__ TE,
                                            const float* __restrict__ wf,
                                            float* __restrict__ Mt,
                                            float* __restrict__ Mrow) {
  __shared__ float red[4][NT];
  int tid = threadIdx.x;
  int q = __builtin_amdgcn_readfirstlane(tid >> 8);
  int c = tid & 255, lane = tid & 63, blk = blockIdx.x;

  const float* wrow = wf + blk * NE;
  float4 wa = *(const float4*)(wrow + 4 * lane);
  float4 wb = make_float4(0.f, 0.f, 0.f, 0.f);
  if (lane < 11) wb = *(const float4*)(wrow + 256 + 4 * lane);
  float acc = 0.f;
#pragma unroll
  for (int k = 0; k < 16; ++k) {
    int ec = q + 4 * k;
    float wx = rdlane(wa.x, ec), wy = rdlane(wa.y, ec);
    float wz = rdlane(wa.z, ec), ww = rdlane(wa.w, ec);
    const float* tp = TE + 4 * ec * NT + c;
    acc = fmaf(tp[0], wx, acc);
    acc = fmaf(tp[NT], wy, acc);
    acc = fmaf(tp[2 * NT], wz, acc);
    acc = fmaf(tp[3 * NT], ww, acc);
  }
#pragma unroll
  for (int k = 16; k < 19; ++k) {
    int ec = q + 4 * k;
    if (ec < 75) {
      int l = ec - 64;
      float wx = rdlane(wb.x, l), wy = rdlane(wb.y, l);
      float wz = rdlane(wb.z, l), ww = rdlane(wb.w, l);
      const float* tp = TE + 4 * ec * NT + c;
      acc = fmaf(tp[0], wx, acc);
      acc = fmaf(tp[NT], wy, acc);
      acc = fmaf(tp[2 * NT], wz, acc);
      acc = fmaf(tp[3 * NT], ww, acc);
    }
  }
  red[q][c] = acc;
  __syncthreads();
  if (q == 0) {
    float s = red[0][c] + red[1][c] + red[2][c] + red[3][c];
    Mt[blk * NT + c] = s;
    Mrow[c * NT + blk] = s;
  }
}

// ===== k_G: row blk of G2=(M M^T)*log2e; Gd, Gof, u2.  (r7, proven)
__global__ __launch_bounds__(1024) void k_G(const float* __restrict__ Mt,
                                            const float* __restrict__ Mrow,
                                            const float* __restrict__ bf,
                                            float* __restrict__ G2,
                                            float* __restrict__ u2,
                                            float* __restrict__ Gd,
                                            float* __restrict__ Gof) {
  __shared__ float red[4][NT];
  __shared__ float fin2[4][2];
  const float LOG2E = 1.4426950408889634f;
  int tid = threadIdx.x;
  int q = __builtin_amdgcn_readfirstlane(tid >> 8);
  int c = tid & 255, lane = tid & 63, wid = tid >> 6, blk = blockIdx.x;

  const float* mrowp = Mrow + blk * NT;
  float4 ma = *(const float4*)(mrowp + 4 * lane);
  float acc = 0.f;
  int c0 = q * 16;
#pragma unroll
  for (int k = 0; k < 16; ++k) {
    int fc = c0 + k;
    float mx = rdlane(ma.x, fc), my = rdlane(ma.y, fc);
    float mz = rdlane(ma.z, fc), mw = rdlane(ma.w, fc);
    const float* tp = Mt + 4 * fc * NT + c;
    acc = fmaf(tp[0], mx, acc);
    acc = fmaf(tp[NT], my, acc);
    acc = fmaf(tp[2 * NT], mz, acc);
    acc = fmaf(tp[3 * NT], mw, acc);
  }
  red[q][c] = acc;
  __syncthreads();
  if (q == 0) {
    float g = (red[0][c] + red[1][c] + red[2][c] + red[3][c]) * LOG2E;
    G2[blk * NT + c] = g;
    if (c == blk) Gd[blk] = g;
    float v = (c == blk) ? -3.0e38f : g;
#pragma unroll
    for (int off = 32; off > 0; off >>= 1) v = fmaxf(v, __shfl_down(v, off, 64));
    if (lane == 0) fin2[wid][0] = v;
    float p = mrowp[c] * bf[c];
#pragma unroll
    for (int off = 32; off > 0; off >>= 1) p += __shfl_down(p, off, 64);
    if (lane == 0) fin2[wid][1] = p;
  }
  __syncthreads();
  if (tid == 0) {
    float gof = fmaxf(fmaxf(fin2[0][0], fin2[1][0]), fmaxf(fin2[2][0], fin2[3][0]));
    Gof[blk] = fmaxf(gof, 0.f);
    u2[blk] = (fin2[0][1] + fin2[1][1] + fin2[2][1] + fin2[3][1]) * LOG2E;
  }
}

// ===== k_main: r7 macro-structure (proven absmax 0.0), with (a) batch pair
// packed into f32x2 -> v_pk_fma_f32, (b) ave_req matvec merged into pass D.
__global__ __launch_bounds__(1024, 8) void k_main(
    const float* __restrict__ req, const float* __restrict__ wsdl,
    const float* __restrict__ Mrow, const float* __restrict__ G2,
    const float* __restrict__ u2, const float* __restrict__ Gd,
    const float* __restrict__ Gof, const float* __restrict__ bf,
    float* __restrict__ out) {
  __shared__ f32x2 RED[4][NT];   // pass D denoms / pass S sums / pass B y
  __shared__ f32x2 AV[4][NT];    // pass D ave_req partials (persist to epilogue)
  __shared__ f32x2 L2s[NT];      // NEGATED log-denoms per column
  __shared__ f32x2 Q2s[NT];
  __shared__ float finU[16];
  __shared__ float fin[16][6];

  int tid = threadIdx.x, q = tid >> 8, c = tid & 255;
  int lane = tid & 63, wid = tid >> 6;
  int blk = blockIdx.x, b0 = blk * NBATCH, i0 = q * 64;

  float wb0 = wsdl[b0 * NT + c], wb1 = wsdl[(b0 + 1) * NT + c];
  float rc0 = req[b0 * NT + c], rc1 = req[(b0 + 1) * NT + c];
  float uc = u2[c], gd = Gd[c], gof = Gof[c];

  // Lane-distributed vectors over this quad's index range.
  float rv0 = req[b0 * NT + i0 + lane], rv1 = req[(b0 + 1) * NT + i0 + lane];
  float wv0 = wsdl[b0 * NT + i0 + lane], wv1 = wsdl[(b0 + 1) * NT + i0 + lane];
  float uv = u2[i0 + lane];

  // up = max_i max(u_i, 0): the 16 waves' uv registers cover all 256 i.
  {
    float um = fmaxf(uv, 0.f);
#pragma unroll
    for (int off = 32; off > 0; off >>= 1) um = fmaxf(um, __shfl_down(um, off, 64));
    if (lane == 0) finU[wid] = um;
  }
  __syncthreads();
  float up = finU[0];
#pragma unroll
  for (int w = 1; w < 16; ++w) up = fmaxf(up, finU[w]);

  // Safe softmax upper bound per (batch, column c) — proven absmax 0.0:
  float mh0 = fmaxf(rc0 * fmaf(wb0, gd, uc), fmaf(wb0, gof, up));
  float mh1 = fmaxf(rc1 * fmaf(wb1, gd, uc), fmaf(wb1, gof, up));

  const f32x2 wbp = {wb0, wb1};
  const f32x2 nmhp = {-mh0, -mh1};
  const f32x2 rcp = {rc0, rc1};
  const f32x2 ucp = {uc, uc};

  // ---- Pass D: column denominators + ave_req matvec (merged) ----
  f32x2 dp = {0.f, 0.f}, ap = {0.f, 0.f};
#pragma unroll 8
  for (int ii = 0; ii < 64; ++ii) {
    float g = G2[(i0 + ii) * NT + c];     // coalesced
    float mk = Mrow[(i0 + ii) * NT + c];  // coalesced
    float su = rdlane(uv, ii);
    f32x2 sp = {rdlane(rv0, ii), rdlane(rv1, ii)};
    f32x2 hp = pk_fma(wbp, (f32x2){g, g}, (f32x2){su, su});
    f32x2 vp = pk_fma(sp, hp, nmhp);
    dp += (f32x2){EXP2F(vp.x), EXP2F(vp.y)};
    ap = pk_fma(sp, (f32x2){mk, mk}, ap);
  }
  RED[q][c] = dp;
  AV[q][c] = ap;
  __syncthreads();
  if (q == 0) {
    f32x2 A = RED[0][c] + RED[1][c] + RED[2][c] + RED[3][c];
    f32x2 L;  // negated: -(mh + log2(denom))
    L.x = -(mh0 + LOG2F(A.x));
    L.y = -(mh1 + LOG2F(A.y));
    L2s[c] = L;
  }
  __syncthreads();
  f32x2 Lq = L2s[i0 + lane];  // negated L for column i0+lane
  float Lv0 = Lq.x, Lv1 = Lq.y;

  // ---- Pass S: row-sums of softmaxed att (row i=c), j over quad range ----
  f32x2 Sp = {0.f, 0.f};
#pragma unroll 8
  for (int jj = 0; jj < 64; ++jj) {
    float g = G2[(i0 + jj) * NT + c];  // G[c][j] by symmetry; coalesced
    f32x2 wp = {rdlane(wv0, jj), rdlane(wv1, jj)};
    f32x2 nlp = {rdlane(Lv0, jj), rdlane(Lv1, jj)};  // already negated
    f32x2 hp = pk_fma(wp, (f32x2){g, g}, ucp);
    f32x2 vp = pk_fma(rcp, hp, nlp);
    Sp += (f32x2){EXP2F(vp.x), EXP2F(vp.y)};
  }
  RED[q][c] = Sp;
  __syncthreads();
  if (q == 0) {
    f32x2 A = RED[0][c] + RED[1][c] + RED[2][c] + RED[3][c];
    Q2s[c] = A * rcp;
  }
  __syncthreads();
  f32x2 Qq = Q2s[i0 + lane];
  float Qv0 = Qq.x, Qv1 = Qq.y;

  // ---- Pass B: ave_wsdl = (qv/T)@M + bf (ave_req already done in pass D) ----
  f32x2 yp = {0.f, 0.f};
#pragma unroll 8
  for (int tt = 0; tt < 64; ++tt) {
    float mk = Mrow[(i0 + tt) * NT + c];  // coalesced
    f32x2 pp = {rdlane(Qv0, tt), rdlane(Qv1, tt)};
    yp = pk_fma(pp, (f32x2){mk, mk}, yp);
  }
  RED[q][c] = yp;
  __syncthreads();
  float st[6];
  {
    f32x2 As = AV[0][c] + AV[1][c] + AV[2][c] + AV[3][c];
    f32x2 Ws = RED[0][c] + RED[1][c] + RED[2][c] + RED[3][c];
    float bfc = bf[c];
    const float invT = 1.0f / NT;
    float avr0 = fmaf(As.x, invT, bfc), avr1 = fmaf(As.y, invT, bfc);
    float avw0 = fmaf(Ws.x, invT, bfc), avw1 = fmaf(Ws.y, invT, bfc);
    st[0] = avr0 * avw0; st[1] = avr0 * avr0; st[2] = avw0 * avw0;
    st[3] = avr1 * avw1; st[4] = avr1 * avr1; st[5] = avw1 * avw1;
  }
  // 4x quad replication of each c cancels in the final ratio.
#pragma unroll
  for (int k = 0; k < 6; ++k)
#pragma unroll
    for (int off = 32; off > 0; off >>= 1) st[k] += __shfl_down(st[k], off, 64);
  if (lane == 0)
#pragma unroll
    for (int k = 0; k < 6; ++k) fin[wid][k] = st[k];
  __syncthreads();
  if (tid < NBATCH) {
    int bb = tid;
    float N = 0.f, A = 0.f, C = 0.f;
    for (int w = 0; w < 16; ++w) {
      N += fin[w][3 * bb + 0];
      A += fin[w][3 * bb + 1];
      C += fin[w][3 * bb + 2];
    }
    out[b0 + bb] = N / fmaxf(sqrtf(A) * sqrtf(C), 1e-8f) * 3.0f;
  }
}

extern "C" void kernel_launch(void* const* d_in, const int* in_sizes, int n_in,
                              void* d_out, int out_size, void* d_ws, size_t ws_size,
                              hipStream_t stream) {
  const float* req  = (const float*)d_in[0];
  const float* wsdl = (const float*)d_in[1];
  const float* TE   = (const float*)d_in[2];
  const float* wf   = (const float*)d_in[3];
  const float* bf   = (const float*)d_in[4];
  float* out = (float*)d_out;

  // ws: [Mt | Mrow | G2 | u2 | Gd | Gof]
  float* Mt   = (float*)d_ws;
  float* Mrow = Mt + NT * NT;
  float* G2   = Mrow + NT * NT;
  float* u2   = G2 + NT * NT;
  float* Gd   = u2 + NT;
  float* Gof  = Gd + NT;

  k_M<<<NT, 1024, 0, stream>>>(TE, wf, Mt, Mrow);
  k_G<<<NT, 1024, 0, stream>>>(Mt, Mrow, bf, G2, u2, Gd, Gof);
  k_main<<<NB / NBATCH, 1024, 0, stream>>>(req, wsdl, Mrow, G2, u2, Gd, Gof,
                                           bf, out);
}

// Round 9
// 119.381 us; speedup vs baseline: 1.0945x; 1.0945x over previous
//
#include <hip/hip_runtime.h>
#include <math.h>

constexpr int NB = 1024;   // batch
constexpr int NT = 256;    // topic_size
constexpr int NE = 300;    // embedding_size
constexpr int NBATCH = 2;  // batches per k_main block

#if defined(__has_builtin)
#if __has_builtin(__builtin_amdgcn_exp2f)
#define EXP2F(x) __builtin_amdgcn_exp2f(x)
#else
#define EXP2F(x) exp2f(x)
#endif
#if __has_builtin(__builtin_amdgcn_logf)
#define LOG2F(x) __builtin_amdgcn_logf(x)
#else
#define LOG2F(x) log2f(x)
#endif
#else
#define EXP2F(x) exp2f(x)
#define LOG2F(x) log2f(x)
#endif

__device__ __forceinline__ float rdlane(float v, int l) {
  return __uint_as_float(__builtin_amdgcn_readlane(__float_as_uint(v), l));
}

// ===== k_M: column blk of M. Mt[blk][t]=sum_e TE[e,t]*wf[blk,e].  (r7, proven)
__global__ __launch_bounds__(1024) void k_M(const float* __restrict__ TE,
                                            const float* __restrict__ wf,
                                            float* __restrict__ Mt,
                                            float* __restrict__ Mrow) {
  __shared__ float red[4][NT];
  int tid = threadIdx.x;
  int q = __builtin_amdgcn_readfirstlane(tid >> 8);
  int c = tid & 255, lane = tid & 63, blk = blockIdx.x;

  const float* wrow = wf + blk * NE;
  float4 wa = *(const float4*)(wrow + 4 * lane);
  float4 wb = make_float4(0.f, 0.f, 0.f, 0.f);
  if (lane < 11) wb = *(const float4*)(wrow + 256 + 4 * lane);
  float acc = 0.f;
#pragma unroll
  for (int k = 0; k < 16; ++k) {  // chunks q+4k <= 63
    int ec = q + 4 * k;
    float wx = rdlane(wa.x, ec), wy = rdlane(wa.y, ec);
    float wz = rdlane(wa.z, ec), ww = rdlane(wa.w, ec);
    const float* tp = TE + 4 * ec * NT + c;
    acc = fmaf(tp[0], wx, acc);
    acc = fmaf(tp[NT], wy, acc);
    acc = fmaf(tp[2 * NT], wz, acc);
    acc = fmaf(tp[3 * NT], ww, acc);
  }
#pragma unroll
  for (int k = 16; k < 19; ++k) {  // chunks 64..74
    int ec = q + 4 * k;
    if (ec < 75) {  // wave-uniform
      int l = ec - 64;
      float wx = rdlane(wb.x, l), wy = rdlane(wb.y, l);
      float wz = rdlane(wb.z, l), ww = rdlane(wb.w, l);
      const float* tp = TE + 4 * ec * NT + c;
      acc = fmaf(tp[0], wx, acc);
      acc = fmaf(tp[NT], wy, acc);
      acc = fmaf(tp[2 * NT], wz, acc);
      acc = fmaf(tp[3 * NT], ww, acc);
    }
  }
  red[q][c] = acc;
  __syncthreads();
  if (q == 0) {
    float s = red[0][c] + red[1][c] + red[2][c] + red[3][c];
    Mt[blk * NT + c] = s;    // coalesced
    Mrow[c * NT + blk] = s;  // scattered, one-time
  }
}

// ===== k_G: row blk of G2=(M M^T)*log2e; Gd (diag), Gof (off-diag row max,
// clamped >=0), u2=(M bf)*log2e.  (r7, proven)
__global__ __launch_bounds__(1024) void k_G(const float* __restrict__ Mt,
                                            const float* __restrict__ Mrow,
                                            const float* __restrict__ bf,
                                            float* __restrict__ G2,
                                            float* __restrict__ u2,
                                            float* __restrict__ Gd,
                                            float* __restrict__ Gof) {
  __shared__ float red[4][NT];
  __shared__ float fin2[4][2];
  const float LOG2E = 1.4426950408889634f;
  int tid = threadIdx.x;
  int q = __builtin_amdgcn_readfirstlane(tid >> 8);
  int c = tid & 255, lane = tid & 63, wid = tid >> 6, blk = blockIdx.x;

  const float* mrowp = Mrow + blk * NT;
  float4 ma = *(const float4*)(mrowp + 4 * lane);
  float acc = 0.f;
  int c0 = q * 16;
#pragma unroll
  for (int k = 0; k < 16; ++k) {
    int fc = c0 + k;  // SGPR
    float mx = rdlane(ma.x, fc), my = rdlane(ma.y, fc);
    float mz = rdlane(ma.z, fc), mw = rdlane(ma.w, fc);
    const float* tp = Mt + 4 * fc * NT + c;
    acc = fmaf(tp[0], mx, acc);
    acc = fmaf(tp[NT], my, acc);
    acc = fmaf(tp[2 * NT], mz, acc);
    acc = fmaf(tp[3 * NT], mw, acc);
  }
  red[q][c] = acc;
  __syncthreads();
  if (q == 0) {
    float g = (red[0][c] + red[1][c] + red[2][c] + red[3][c]) * LOG2E;
    G2[blk * NT + c] = g;
    if (c == blk) Gd[blk] = g;
    float v = (c == blk) ? -3.0e38f : g;
#pragma unroll
    for (int off = 32; off > 0; off >>= 1) v = fmaxf(v, __shfl_down(v, off, 64));
    if (lane == 0) fin2[wid][0] = v;
    float p = mrowp[c] * bf[c];  // coalesced
#pragma unroll
    for (int off = 32; off > 0; off >>= 1) p += __shfl_down(p, off, 64);
    if (lane == 0) fin2[wid][1] = p;
  }
  __syncthreads();
  if (tid == 0) {
    float gof = fmaxf(fmaxf(fin2[0][0], fin2[1][0]), fmaxf(fin2[2][0], fin2[3][0]));
    Gof[blk] = fmaxf(gof, 0.f);
    u2[blk] = (fin2[0][1] + fin2[1][1] + fin2[2][1] + fin2[3][1]) * LOG2E;
  }
}

// ===== k_main: 2 batches/block, grid 512 -> 2 blocks/CU (32 waves/CU).
// r7 verbatim (proven 53.3 us, VALUBusy ~70%, absmax 0.0, conflicts 0).
// NOTE: scalar ops only — f32x2 packing under __launch_bounds__(1024,8)
// spills 64 B/thread to scratch (r8: WRITE_SIZE 16 KB -> 32 MB, +25% time).
__global__ __launch_bounds__(1024, 8) void k_main(
    const float* __restrict__ req, const float* __restrict__ wsdl,
    const float* __restrict__ Mrow, const float* __restrict__ G2,
    const float* __restrict__ u2, const float* __restrict__ Gd,
    const float* __restrict__ Gof, const float* __restrict__ bf,
    float* __restrict__ out) {
  __shared__ float RA[4][NT], RB[4][NT], RC[4][NT], RD[4][NT];
  __shared__ float2 L2s[NT];
  __shared__ float2 Q2s[NT];
  __shared__ float finU[16];
  __shared__ float fin[16][6];

  int tid = threadIdx.x, q = tid >> 8, c = tid & 255;
  int lane = tid & 63, wid = tid >> 6;
  int blk = blockIdx.x, b0 = blk * NBATCH, i0 = q * 64;

  float wb0 = wsdl[b0 * NT + c], wb1 = wsdl[(b0 + 1) * NT + c];
  float rc0 = req[b0 * NT + c], rc1 = req[(b0 + 1) * NT + c];
  float uc = u2[c], gd = Gd[c], gof = Gof[c];

  // Lane-distributed vectors over this quad's index range.
  float rv0 = req[b0 * NT + i0 + lane], rv1 = req[(b0 + 1) * NT + i0 + lane];
  float wv0 = wsdl[b0 * NT + i0 + lane], wv1 = wsdl[(b0 + 1) * NT + i0 + lane];
  float uv = u2[i0 + lane];

  // up = max_i max(u_i, 0): the 16 waves' uv registers cover all 256 i.
  {
    float um = fmaxf(uv, 0.f);
#pragma unroll
    for (int off = 32; off > 0; off >>= 1) um = fmaxf(um, __shfl_down(um, off, 64));
    if (lane == 0) finU[wid] = um;
  }
  __syncthreads();
  float up = finU[0];
#pragma unroll
  for (int w = 1; w < 16; ++w) up = fmaxf(up, finU[w]);

  // Safe softmax upper bound per (batch, column c) — proven absmax 0.0:
  float mh0 = fmaxf(rc0 * fmaf(wb0, gd, uc), fmaf(wb0, gof, up));
  float mh1 = fmaxf(rc1 * fmaf(wb1, gd, uc), fmaf(wb1, gof, up));

  // ---- Pass D: column denominators ----
  float d0 = 0.f, d1 = 0.f;
#pragma unroll 8
  for (int ii = 0; ii < 64; ++ii) {
    float g = G2[(i0 + ii) * NT + c];  // coalesced
    float su = rdlane(uv, ii);
    float s0 = rdlane(rv0, ii), s1 = rdlane(rv1, ii);
    d0 += EXP2F(fmaf(s0, fmaf(wb0, g, su), -mh0));
    d1 += EXP2F(fmaf(s1, fmaf(wb1, g, su), -mh1));
  }
  RA[q][c] = d0;
  RB[q][c] = d1;
  __syncthreads();
  if (q == 0) {
    float2 L;
    L.x = mh0 + LOG2F(RA[0][c] + RA[1][c] + RA[2][c] + RA[3][c]);
    L.y = mh1 + LOG2F(RB[0][c] + RB[1][c] + RB[2][c] + RB[3][c]);
    L2s[c] = L;
  }
  __syncthreads();
  float2 Lq = L2s[i0 + lane];
  float Lv0 = Lq.x, Lv1 = Lq.y;

  // ---- Pass S: row-sums of softmaxed att (row i=c), j over quad range ----
  float S0 = 0.f, S1 = 0.f;
#pragma unroll 8
  for (int jj = 0; jj < 64; ++jj) {
    float g = G2[(i0 + jj) * NT + c];  // G[c][j] by symmetry; coalesced
    float w0 = rdlane(wv0, jj), w1 = rdlane(wv1, jj);
    float l0 = rdlane(Lv0, jj), l1 = rdlane(Lv1, jj);
    S0 += EXP2F(fmaf(rc0, fmaf(w0, g, uc), -l0));
    S1 += EXP2F(fmaf(rc1, fmaf(w1, g, uc), -l1));
  }
  RA[q][c] = S0;
  RB[q][c] = S1;
  __syncthreads();
  if (q == 0) {
    float2 qv;
    qv.x = (RA[0][c] + RA[1][c] + RA[2][c] + RA[3][c]) * rc0;
    qv.y = (RB[0][c] + RB[1][c] + RB[2][c] + RB[3][c]) * rc1;
    Q2s[c] = qv;
  }
  __syncthreads();
  float2 Qq = Q2s[i0 + lane];
  float Qv0 = Qq.x, Qv1 = Qq.y;

  // ---- Pass B: ave_req = (r/T)@M + bf, ave_wsdl = (qv/T)@M + bf ----
  float a0 = 0.f, a1 = 0.f, y0 = 0.f, y1 = 0.f;
#pragma unroll 8
  for (int tt = 0; tt < 64; ++tt) {
    float mk = Mrow[(i0 + tt) * NT + c];  // coalesced
    float s0 = rdlane(rv0, tt), s1 = rdlane(rv1, tt);
    float p0 = rdlane(Qv0, tt), p1 = rdlane(Qv1, tt);
    a0 = fmaf(s0, mk, a0);
    a1 = fmaf(s1, mk, a1);
    y0 = fmaf(p0, mk, y0);
    y1 = fmaf(p1, mk, y1);
  }
  RA[q][c] = a0;
  RB[q][c] = a1;
  RC[q][c] = y0;
  RD[q][c] = y1;
  __syncthreads();
  float st[6];
  {
    float bfc = bf[c];
    const float invT = 1.0f / NT;
    float avr0 = fmaf(RA[0][c] + RA[1][c] + RA[2][c] + RA[3][c], invT, bfc);
    float avr1 = fmaf(RB[0][c] + RB[1][c] + RB[2][c] + RB[3][c], invT, bfc);
    float avw0 = fmaf(RC[0][c] + RC[1][c] + RC[2][c] + RC[3][c], invT, bfc);
    float avw1 = fmaf(RD[0][c] + RD[1][c] + RD[2][c] + RD[3][c], invT, bfc);
    st[0] = avr0 * avw0; st[1] = avr0 * avr0; st[2] = avw0 * avw0;
    st[3] = avr1 * avw1; st[4] = avr1 * avr1; st[5] = avw1 * avw1;
  }
  // 4x quad replication of each c cancels in the final ratio.
#pragma unroll
  for (int k = 0; k < 6; ++k)
#pragma unroll
    for (int off = 32; off > 0; off >>= 1) st[k] += __shfl_down(st[k], off, 64);
  if (lane == 0)
#pragma unroll
    for (int k = 0; k < 6; ++k) fin[wid][k] = st[k];
  __syncthreads();
  if (tid < NBATCH) {
    int bb = tid;
    float N = 0.f, A = 0.f, C = 0.f;
    for (int w = 0; w < 16; ++w) {
      N += fin[w][3 * bb + 0];
      A += fin[w][3 * bb + 1];
      C += fin[w][3 * bb + 2];
    }
    out[b0 + bb] = N / fmaxf(sqrtf(A) * sqrtf(C), 1e-8f) * 3.0f;
  }
}

extern "C" void kernel_launch(void* const* d_in, const int* in_sizes, int n_in,
                              void* d_out, int out_size, void* d_ws, size_t ws_size,
                              hipStream_t stream) {
  const float* req  = (const float*)d_in[0];
  const float* wsdl = (const float*)d_in[1];
  const float* TE   = (const float*)d_in[2];
  const float* wf   = (const float*)d_in[3];
  const float* bf   = (const float*)d_in[4];
  float* out = (float*)d_out;

  // ws: [Mt | Mrow | G2 | u2 | Gd | Gof]
  float* Mt   = (float*)d_ws;
  float* Mrow = Mt + NT * NT;
  float* G2   = Mrow + NT * NT;
  float* u2   = G2 + NT * NT;
  float* Gd   = u2 + NT;
  float* Gof  = Gd + NT;

  k_M<<<NT, 1024, 0, stream>>>(TE, wf, Mt, Mrow);
  k_G<<<NT, 1024, 0, stream>>>(Mt, Mrow, bf, G2, u2, Gd, Gof);
  k_main<<<NB / NBATCH, 1024, 0, stream>>>(req, wsdl, Mrow, G2, u2, Gd, Gof,
                                           bf, out);
}